// Round 2
// baseline (405.344 us; speedup 1.0000x reference)
//
#include <hip/hip_runtime.h>

// ---------------------------------------------------------------------------
// DomainAlignmentModel: 3-branch GCN-ish model on MI355X.
// Identity used: spmm(x) @ W == spmm(x @ W)  -> project first (128->64),
// fuse homo+het projected features into one N x 128 buffer, 1 SPMM per layer.
// Adjacency: y[i] = dinv[i]*( sum_{c in nbr(i)} dinv[c]*P[c] + dinv[i]*P[i] )
// with deg = in-degree(col)+1 (self loop), dinv = rsqrt(deg).
//
// R1: GEMM loop-interchanged — 16 row-accumulators per lane (16 independent
// FMA chains), k outer in chunks of 4; W chunk in 4 VGPRs, x via wave-uniform
// scalar loads. R0 was latency-bound (VALUBusy 22%, 4-deep acc chains +
// unresident 128-entry W array).
// ---------------------------------------------------------------------------

__global__ __launch_bounds__(256) void build_adj_kernel(
    const int* __restrict__ ei, int E, int* __restrict__ deg,
    int* __restrict__ cur, int* __restrict__ bucket)
{
    int e = blockIdx.x * 256 + threadIdx.x;
    if (e >= E) return;
    int r = ei[e];          // edge_index[0][e]  (dest of the scatter-add)
    int c = ei[E + e];      // edge_index[1][e]  (source / degree node)
    atomicAdd(&deg[c], 1);
    int pos = atomicAdd(&cur[r], 1);
    if (pos < 64) bucket[(size_t)r * 64 + pos] = c;
}

__global__ __launch_bounds__(256) void dinv_kernel(
    const int* __restrict__ deg, float* __restrict__ dinv, int N)
{
    int i = blockIdx.x * 256 + threadIdx.x;
    if (i < N) dinv[i] = 1.0f / sqrtf((float)deg[i] + 1.0f);
}

// One wave per 16 rows; lane = output column (0..63). blockIdx.y = branch:
//   b=0 -> outP[:,0:64], b=1 -> outP[:,64:128], b=2 -> outF with relu(alpha*v).
// k outer (chunks of 4): per chunk load 4 W values (vector, L1) and 16
// wave-uniform x chunks (scalar loads) -> 64 independent FMAs.
template<int K>
__global__ __launch_bounds__(256, 6) void gemm3_kernel(
    const float* __restrict__ in0, const float* __restrict__ in1, const float* __restrict__ in2,
    const float* __restrict__ w0, const float* __restrict__ w1, const float* __restrict__ w2,
    float* __restrict__ outP, float* __restrict__ outF,
    const float* __restrict__ alphaF, int N)
{
    const int b = blockIdx.y;
    const float* __restrict__ in = (b == 0) ? in0 : ((b == 1) ? in1 : in2);
    const float* __restrict__ W  = (b == 0) ? w0  : ((b == 1) ? w1  : w2);
    const int lane = threadIdx.x & 63;
    const int row0 = __builtin_amdgcn_readfirstlane(
        blockIdx.x * 64 + (threadIdx.x >> 6) * 16);
    if (row0 >= N) return;
    const float alpha = alphaF[0];

    float acc[16];
    #pragma unroll
    for (int r = 0; r < 16; ++r) acc[r] = 0.f;

    if (row0 + 16 <= N) {
        const float* __restrict__ xb = in + (size_t)row0 * K;
        #pragma unroll 1
        for (int k = 0; k < K; k += 4) {
            const float wv0 = W[(size_t)(k + 0) * 64 + lane];
            const float wv1 = W[(size_t)(k + 1) * 64 + lane];
            const float wv2 = W[(size_t)(k + 2) * 64 + lane];
            const float wv3 = W[(size_t)(k + 3) * 64 + lane];
            #pragma unroll
            for (int r = 0; r < 16; ++r) {
                const float* __restrict__ xr = xb + r * K + k;  // wave-uniform
                acc[r] = fmaf(xr[3], wv3,
                         fmaf(xr[2], wv2,
                         fmaf(xr[1], wv1,
                         fmaf(xr[0], wv0, acc[r]))));
            }
        }
        if (b < 2) {
            #pragma unroll
            for (int r = 0; r < 16; ++r)
                outP[(size_t)(row0 + r) * 128 + b * 64 + lane] = acc[r];
        } else {
            #pragma unroll
            for (int r = 0; r < 16; ++r)
                outF[(size_t)(row0 + r) * 64 + lane] = fmaxf(alpha * acc[r], 0.f);
        }
    } else {
        const int rmax = N - row0;
        for (int r = 0; r < rmax; ++r) {
            const float* __restrict__ xr = in + (size_t)(row0 + r) * K;
            float a = 0.f;
            for (int k = 0; k < K; ++k) a = fmaf(xr[k], W[(size_t)k * 64 + lane], a);
            if (b < 2) outP[(size_t)(row0 + r) * 128 + b * 64 + lane] = a;
            else       outF[(size_t)(row0 + r) * 64 + lane] = fmaxf(alpha * a, 0.f);
        }
    }
}

// SPMM over fused N x 128 features. One wave per dest node; lane holds
// features (2*lane, 2*lane+1) as float2. Lanes 0-31 -> homo half, 32-63 -> het.
__global__ __launch_bounds__(256) void spmm1_kernel(
    const float* __restrict__ P, const int* __restrict__ bucket, const int* __restrict__ cnt,
    const float* __restrict__ dinv, float* __restrict__ homo1, float* __restrict__ het1,
    const float* __restrict__ aH, const float* __restrict__ aT, int N)
{
    const int i = blockIdx.x * 4 + (threadIdx.x >> 6);
    if (i >= N) return;
    const int lane = threadIdx.x & 63;
    const float2* __restrict__ P2 = (const float2*)P;
    const float di = dinv[i];
    const float2 ps = P2[(size_t)i * 64 + lane];
    int n = cnt[i]; if (n > 64) n = 64;
    const int* __restrict__ brow = bucket + (size_t)i * 64;
    float ax = 0.f, ay = 0.f;
    for (int k0 = 0; k0 < n; k0 += 8) {
        #pragma unroll
        for (int j = 0; j < 8; ++j) {
            const int k = k0 + j;
            const bool act = (k < n);
            const int c = act ? brow[k] : i;       // broadcast load (uniform)
            const float dc = act ? dinv[c] : 0.f;  // broadcast gather
            const float2 v = P2[(size_t)c * 64 + lane];
            ax += dc * v.x; ay += dc * v.y;
        }
    }
    const float yx = di * (ax + di * ps.x);
    const float yy = di * (ay + di * ps.y);
    float ox, oy; float* dst;
    if (lane < 32) {
        const float a = aH[0];
        ox = fmaxf(a * yx, 0.f); oy = fmaxf(a * yy, 0.f);
        dst = homo1 + (size_t)i * 64 + 2 * lane;
    } else {
        const float a = aT[0];
        ox = fmaxf(a * (ps.x - yx), 0.f); oy = fmaxf(a * (ps.y - yy), 0.f);
        dst = het1 + (size_t)i * 64 + 2 * (lane - 32);
    }
    *(float2*)dst = make_float2(ox, oy);
}

__global__ __launch_bounds__(256) void spmm2_kernel(
    const float* __restrict__ Q, const int* __restrict__ bucket, const int* __restrict__ cnt,
    const float* __restrict__ dinv, const float* __restrict__ full2,
    float* __restrict__ outComb, float* __restrict__ outHomo, float* __restrict__ outHet,
    const float* __restrict__ aH, const float* __restrict__ aT,
    const float* __restrict__ wH, const float* __restrict__ wF, const float* __restrict__ wT,
    int N)
{
    const int i = blockIdx.x * 4 + (threadIdx.x >> 6);
    if (i >= N) return;
    const int lane = threadIdx.x & 63;
    const float2* __restrict__ Q2 = (const float2*)Q;
    const float di = dinv[i];
    const float2 qs = Q2[(size_t)i * 64 + lane];
    int n = cnt[i]; if (n > 64) n = 64;
    const int* __restrict__ brow = bucket + (size_t)i * 64;
    float ax = 0.f, ay = 0.f;
    for (int k0 = 0; k0 < n; k0 += 8) {
        #pragma unroll
        for (int j = 0; j < 8; ++j) {
            const int k = k0 + j;
            const bool act = (k < n);
            const int c = act ? brow[k] : i;
            const float dc = act ? dinv[c] : 0.f;
            const float2 v = Q2[(size_t)c * 64 + lane];
            ax += dc * v.x; ay += dc * v.y;
        }
    }
    const float yx = di * (ax + di * qs.x);
    const float yy = di * (ay + di * qs.y);
    float vx, vy; float* dst;
    if (lane < 32) {
        const float a = aH[0];
        vx = fmaxf(a * yx, 0.f); vy = fmaxf(a * yy, 0.f);
        dst = outHomo + (size_t)i * 64 + 2 * lane;
    } else {
        const float a = aT[0];
        vx = fmaxf(a * (qs.x - yx), 0.f); vy = fmaxf(a * (qs.y - yy), 0.f);
        dst = outHet + (size_t)i * 64 + 2 * (lane - 32);
    }
    *(float2*)dst = make_float2(vx, vy);
    // combined = wH*h_homo + wF*h_full + wT*h_het; exchange halves across lane^32
    const float tx = __shfl_xor(vx, 32);
    const float ty = __shfl_xor(vy, 32);
    if (lane < 32) {
        const float2 f2 = ((const float2*)full2)[(size_t)i * 32 + lane];
        const float cwh = wH[0], cwf = wF[0], cwt = wT[0];
        const float cx = cwh * vx + cwf * f2.x + cwt * tx;
        const float cy = cwh * vy + cwf * f2.y + cwt * ty;
        *(float2*)(outComb + (size_t)i * 64 + 2 * lane) = make_float2(cx, cy);
    }
}

extern "C" void kernel_launch(void* const* d_in, const int* in_sizes, int n_in,
                              void* d_out, int out_size, void* d_ws, size_t ws_size,
                              hipStream_t stream)
{
    const float* x  = (const float*)d_in[0];
    const int*   ei = (const int*)d_in[1];
    const int N = in_sizes[0] / 128;
    const int E = in_sizes[1] / 2;
    const float* homo_W0 = (const float*)d_in[3];
    const float* homo_W1 = (const float*)d_in[4];
    const float* full_W0 = (const float*)d_in[5];
    const float* full_W1 = (const float*)d_in[6];
    const float* het_W0  = (const float*)d_in[7];
    const float* het_W1  = (const float*)d_in[8];
    const float* homo_a0 = (const float*)d_in[9];
    const float* homo_a1 = (const float*)d_in[10];
    const float* full_a0 = (const float*)d_in[11];
    const float* full_a1 = (const float*)d_in[12];
    const float* het_a0  = (const float*)d_in[13];
    const float* het_a1  = (const float*)d_in[14];
    const float* w_homo  = (const float*)d_in[15];
    const float* w_full  = (const float*)d_in[16];
    const float* w_het   = (const float*)d_in[17];

    char* ws = (char*)d_ws;
    size_t off = 0;
    auto alloc = [&](size_t bytes) -> char* {
        char* p = ws + off;
        off = (off + bytes + 511) & ~(size_t)511;
        return p;
    };
    int*   deg    = (int*)alloc((size_t)N * 4);
    int*   cur    = (int*)alloc((size_t)N * 4);
    float* dinv   = (float*)alloc((size_t)N * 4);
    int*   bucket = (int*)alloc((size_t)N * 64 * 4);
    float* P      = (float*)alloc((size_t)N * 128 * 4);
    float* full1  = (float*)alloc((size_t)N * 64 * 4);
    float* homo1  = (float*)alloc((size_t)N * 64 * 4);
    float* het1   = (float*)alloc((size_t)N * 64 * 4);
    float* Q      = P;  // P dead after spmm1; reuse for layer-2 fused features

    float* out      = (float*)d_out;
    float* outComb  = out;
    float* outHomo  = out + (size_t)N * 64;
    float* outFull  = out + (size_t)2 * N * 64;
    float* outHet   = out + (size_t)3 * N * 64;

    hipMemsetAsync(deg, 0, (size_t)N * 4, stream);
    hipMemsetAsync(cur, 0, (size_t)N * 4, stream);

    build_adj_kernel<<<(E + 255) / 256, 256, 0, stream>>>(ei, E, deg, cur, bucket);
    dinv_kernel<<<(N + 255) / 256, 256, 0, stream>>>(deg, dinv, N);

    // Layer 1: P[:,0:64]=x@homo_W0, P[:,64:128]=x@het_W0, full1=relu(af0*x@full_W0)
    gemm3_kernel<128><<<dim3((N + 63) / 64, 3), 256, 0, stream>>>(
        x, x, x, homo_W0, het_W0, full_W0, P, full1, full_a0, N);
    spmm1_kernel<<<(N + 3) / 4, 256, 0, stream>>>(
        P, bucket, cur, dinv, homo1, het1, homo_a0, het_a0, N);

    // Layer 2: Q[:,0:64]=homo1@homo_W1, Q[:,64:128]=het1@het_W1,
    //          h_full = relu(af1*full1@full_W1) written straight to d_out
    gemm3_kernel<64><<<dim3((N + 63) / 64, 3), 256, 0, stream>>>(
        homo1, het1, full1, homo_W1, het_W1, full_W1, Q, outFull, full_a1, N);
    spmm2_kernel<<<(N + 3) / 4, 256, 0, stream>>>(
        Q, bucket, cur, dinv, outFull, outComb, outHomo, outHet,
        homo_a1, het_a1, w_homo, w_full, w_het, N);
}

// Round 3
// 338.925 us; speedup vs baseline: 1.1960x; 1.1960x over previous
//
#include <hip/hip_runtime.h>

// ---------------------------------------------------------------------------
// DomainAlignmentModel: 3-branch GCN-ish model on MI355X.
// spmm(x) @ W == spmm(x @ W) -> project first (128->64), fuse homo+het into
// one N x 128 buffer, 1 SPMM per layer.
// R2 lesson: wave-uniform x loads became scalar s_loads (SGPR=112) and
// latency-starved the VALU (10% busy). R3: x tile staged in LDS, inner loop
// reads rows via broadcast ds_read_b128; layer-1 branches fused (x staged 1x).
// ---------------------------------------------------------------------------

__global__ __launch_bounds__(256) void build_adj_kernel(
    const int* __restrict__ ei, int E, int* __restrict__ deg,
    int* __restrict__ cur, int* __restrict__ bucket)
{
    int e = blockIdx.x * 256 + threadIdx.x;
    if (e >= E) return;
    int r = ei[e];          // edge_index[0][e]  (dest of the scatter-add)
    int c = ei[E + e];      // edge_index[1][e]  (source / degree node)
    atomicAdd(&deg[c], 1);
    int pos = atomicAdd(&cur[r], 1);
    if (pos < 64) bucket[(size_t)r * 64 + pos] = c;
}

__global__ __launch_bounds__(256) void dinv_kernel(
    const int* __restrict__ deg, float* __restrict__ dinv, int N)
{
    int i = blockIdx.x * 256 + threadIdx.x;
    if (i < N) dinv[i] = 1.0f / sqrtf((float)deg[i] + 1.0f);
}

// Layer 1: one block per 64-row tile. x tile (64x128, 32KB) staged in LDS
// once, reused by all 3 branches. Wave w owns rows w*16..w*16+15; lane = col.
// 16 independent acc chains; x via broadcast ds_read_b128 (uniform addr).
__global__ __launch_bounds__(256) void gemm_l1_kernel(
    const float* __restrict__ x,
    const float* __restrict__ wHomo, const float* __restrict__ wHet,
    const float* __restrict__ wFull,
    float* __restrict__ P, float* __restrict__ full1,
    const float* __restrict__ alphaF, int N)
{
    __shared__ float sx[64 * 128];
    const int tid = threadIdx.x;
    const int row0 = blockIdx.x * 64;

    if (row0 + 64 <= N) {
        const float4* __restrict__ src = (const float4*)(x + (size_t)row0 * 128);
        float4* dst = (float4*)sx;
        #pragma unroll
        for (int j = 0; j < 8; ++j) dst[j * 256 + tid] = src[j * 256 + tid];
    } else {
        for (int j = 0; j < 8; ++j) {
            const int idx = j * 256 + tid;        // float4 index; 32 per row
            const int row = row0 + (idx >> 5);
            float4 v = make_float4(0.f, 0.f, 0.f, 0.f);
            if (row < N) v = ((const float4*)x)[(size_t)row * 32 + (idx & 31)];
            ((float4*)sx)[idx] = v;
        }
    }
    __syncthreads();

    const int lane = tid & 63;
    const int rbase = (tid >> 6) * 16;
    const float alpha = alphaF[0];

    #pragma unroll 1
    for (int b = 0; b < 3; ++b) {
        const float* __restrict__ W = (b == 0) ? wHomo : ((b == 1) ? wHet : wFull);
        float acc[16];
        #pragma unroll
        for (int r = 0; r < 16; ++r) acc[r] = 0.f;
        #pragma unroll 1
        for (int k = 0; k < 128; k += 4) {
            const float wv0 = W[(k + 0) * 64 + lane];
            const float wv1 = W[(k + 1) * 64 + lane];
            const float wv2 = W[(k + 2) * 64 + lane];
            const float wv3 = W[(k + 3) * 64 + lane];
            #pragma unroll
            for (int r = 0; r < 16; ++r) {
                const float4 xv = *(const float4*)&sx[(rbase + r) * 128 + k];
                acc[r] = fmaf(xv.w, wv3, fmaf(xv.z, wv2,
                         fmaf(xv.y, wv1, fmaf(xv.x, wv0, acc[r]))));
            }
        }
        #pragma unroll
        for (int r = 0; r < 16; ++r) {
            const int row = row0 + rbase + r;
            if (row < N) {
                if (b < 2) P[(size_t)row * 128 + b * 64 + lane] = acc[r];
                else       full1[(size_t)row * 64 + lane] = fmaxf(alpha * acc[r], 0.f);
            }
        }
    }
}

// Layer 2 (K=64): per-branch inputs differ -> blockIdx.y = branch, each block
// stages its own 64x64 tile (16KB).
__global__ __launch_bounds__(256) void gemm_l2_kernel(
    const float* __restrict__ in0, const float* __restrict__ in1,
    const float* __restrict__ in2,
    const float* __restrict__ w0, const float* __restrict__ w1,
    const float* __restrict__ w2,
    float* __restrict__ Q, float* __restrict__ outF,
    const float* __restrict__ alphaF, int N)
{
    __shared__ float sx[64 * 64];
    const int b = blockIdx.y;
    const float* __restrict__ in = (b == 0) ? in0 : ((b == 1) ? in1 : in2);
    const float* __restrict__ W  = (b == 0) ? w0  : ((b == 1) ? w1  : w2);
    const int tid = threadIdx.x;
    const int row0 = blockIdx.x * 64;

    if (row0 + 64 <= N) {
        const float4* __restrict__ src = (const float4*)(in + (size_t)row0 * 64);
        float4* dst = (float4*)sx;
        #pragma unroll
        for (int j = 0; j < 4; ++j) dst[j * 256 + tid] = src[j * 256 + tid];
    } else {
        for (int j = 0; j < 4; ++j) {
            const int idx = j * 256 + tid;        // float4 index; 16 per row
            const int row = row0 + (idx >> 4);
            float4 v = make_float4(0.f, 0.f, 0.f, 0.f);
            if (row < N) v = ((const float4*)in)[(size_t)row * 16 + (idx & 15)];
            ((float4*)sx)[idx] = v;
        }
    }
    __syncthreads();

    const int lane = tid & 63;
    const int rbase = (tid >> 6) * 16;
    const float alpha = alphaF[0];

    float acc[16];
    #pragma unroll
    for (int r = 0; r < 16; ++r) acc[r] = 0.f;
    #pragma unroll 1
    for (int k = 0; k < 64; k += 4) {
        const float wv0 = W[(k + 0) * 64 + lane];
        const float wv1 = W[(k + 1) * 64 + lane];
        const float wv2 = W[(k + 2) * 64 + lane];
        const float wv3 = W[(k + 3) * 64 + lane];
        #pragma unroll
        for (int r = 0; r < 16; ++r) {
            const float4 xv = *(const float4*)&sx[(rbase + r) * 64 + k];
            acc[r] = fmaf(xv.w, wv3, fmaf(xv.z, wv2,
                     fmaf(xv.y, wv1, fmaf(xv.x, wv0, acc[r]))));
        }
    }
    #pragma unroll
    for (int r = 0; r < 16; ++r) {
        const int row = row0 + rbase + r;
        if (row < N) {
            if (b < 2) Q[(size_t)row * 128 + b * 64 + lane] = acc[r];
            else       outF[(size_t)row * 64 + lane] = fmaxf(alpha * acc[r], 0.f);
        }
    }
}

// SPMM over fused N x 128 features. One wave per dest node; lane holds
// features (2*lane, 2*lane+1) as float2. Lanes 0-31 -> homo half, 32-63 -> het.
__global__ __launch_bounds__(256) void spmm1_kernel(
    const float* __restrict__ P, const int* __restrict__ bucket, const int* __restrict__ cnt,
    const float* __restrict__ dinv, float* __restrict__ homo1, float* __restrict__ het1,
    const float* __restrict__ aH, const float* __restrict__ aT, int N)
{
    const int i = blockIdx.x * 4 + (threadIdx.x >> 6);
    if (i >= N) return;
    const int lane = threadIdx.x & 63;
    const float2* __restrict__ P2 = (const float2*)P;
    const float di = dinv[i];
    const float2 ps = P2[(size_t)i * 64 + lane];
    int n = cnt[i]; if (n > 64) n = 64;
    const int* __restrict__ brow = bucket + (size_t)i * 64;
    float ax = 0.f, ay = 0.f;
    for (int k0 = 0; k0 < n; k0 += 8) {
        #pragma unroll
        for (int j = 0; j < 8; ++j) {
            const int k = k0 + j;
            const bool act = (k < n);
            const int c = act ? brow[k] : i;       // broadcast load (uniform)
            const float dc = act ? dinv[c] : 0.f;  // broadcast gather
            const float2 v = P2[(size_t)c * 64 + lane];
            ax += dc * v.x; ay += dc * v.y;
        }
    }
    const float yx = di * (ax + di * ps.x);
    const float yy = di * (ay + di * ps.y);
    float ox, oy; float* dst;
    if (lane < 32) {
        const float a = aH[0];
        ox = fmaxf(a * yx, 0.f); oy = fmaxf(a * yy, 0.f);
        dst = homo1 + (size_t)i * 64 + 2 * lane;
    } else {
        const float a = aT[0];
        ox = fmaxf(a * (ps.x - yx), 0.f); oy = fmaxf(a * (ps.y - yy), 0.f);
        dst = het1 + (size_t)i * 64 + 2 * (lane - 32);
    }
    *(float2*)dst = make_float2(ox, oy);
}

__global__ __launch_bounds__(256) void spmm2_kernel(
    const float* __restrict__ Q, const int* __restrict__ bucket, const int* __restrict__ cnt,
    const float* __restrict__ dinv, const float* __restrict__ full2,
    float* __restrict__ outComb, float* __restrict__ outHomo, float* __restrict__ outHet,
    const float* __restrict__ aH, const float* __restrict__ aT,
    const float* __restrict__ wH, const float* __restrict__ wF, const float* __restrict__ wT,
    int N)
{
    const int i = blockIdx.x * 4 + (threadIdx.x >> 6);
    if (i >= N) return;
    const int lane = threadIdx.x & 63;
    const float2* __restrict__ Q2 = (const float2*)Q;
    const float di = dinv[i];
    const float2 qs = Q2[(size_t)i * 64 + lane];
    int n = cnt[i]; if (n > 64) n = 64;
    const int* __restrict__ brow = bucket + (size_t)i * 64;
    float ax = 0.f, ay = 0.f;
    for (int k0 = 0; k0 < n; k0 += 8) {
        #pragma unroll
        for (int j = 0; j < 8; ++j) {
            const int k = k0 + j;
            const bool act = (k < n);
            const int c = act ? brow[k] : i;
            const float dc = act ? dinv[c] : 0.f;
            const float2 v = Q2[(size_t)c * 64 + lane];
            ax += dc * v.x; ay += dc * v.y;
        }
    }
    const float yx = di * (ax + di * qs.x);
    const float yy = di * (ay + di * qs.y);
    float vx, vy; float* dst;
    if (lane < 32) {
        const float a = aH[0];
        vx = fmaxf(a * yx, 0.f); vy = fmaxf(a * yy, 0.f);
        dst = outHomo + (size_t)i * 64 + 2 * lane;
    } else {
        const float a = aT[0];
        vx = fmaxf(a * (qs.x - yx), 0.f); vy = fmaxf(a * (qs.y - yy), 0.f);
        dst = outHet + (size_t)i * 64 + 2 * (lane - 32);
    }
    *(float2*)dst = make_float2(vx, vy);
    // combined = wH*h_homo + wF*h_full + wT*h_het; exchange halves across lane^32
    const float tx = __shfl_xor(vx, 32);
    const float ty = __shfl_xor(vy, 32);
    if (lane < 32) {
        const float2 f2 = ((const float2*)full2)[(size_t)i * 32 + lane];
        const float cwh = wH[0], cwf = wF[0], cwt = wT[0];
        const float cx = cwh * vx + cwf * f2.x + cwt * tx;
        const float cy = cwh * vy + cwf * f2.y + cwt * ty;
        *(float2*)(outComb + (size_t)i * 64 + 2 * lane) = make_float2(cx, cy);
    }
}

extern "C" void kernel_launch(void* const* d_in, const int* in_sizes, int n_in,
                              void* d_out, int out_size, void* d_ws, size_t ws_size,
                              hipStream_t stream)
{
    const float* x  = (const float*)d_in[0];
    const int*   ei = (const int*)d_in[1];
    const int N = in_sizes[0] / 128;
    const int E = in_sizes[1] / 2;
    const float* homo_W0 = (const float*)d_in[3];
    const float* homo_W1 = (const float*)d_in[4];
    const float* full_W0 = (const float*)d_in[5];
    const float* full_W1 = (const float*)d_in[6];
    const float* het_W0  = (const float*)d_in[7];
    const float* het_W1  = (const float*)d_in[8];
    const float* homo_a0 = (const float*)d_in[9];
    const float* homo_a1 = (const float*)d_in[10];
    const float* full_a0 = (const float*)d_in[11];
    const float* full_a1 = (const float*)d_in[12];
    const float* het_a0  = (const float*)d_in[13];
    const float* het_a1  = (const float*)d_in[14];
    const float* w_homo  = (const float*)d_in[15];
    const float* w_full  = (const float*)d_in[16];
    const float* w_het   = (const float*)d_in[17];

    char* ws = (char*)d_ws;
    size_t off = 0;
    auto alloc = [&](size_t bytes) -> char* {
        char* p = ws + off;
        off = (off + bytes + 511) & ~(size_t)511;
        return p;
    };
    int*   deg    = (int*)alloc((size_t)N * 4);
    int*   cur    = (int*)alloc((size_t)N * 4);
    float* dinv   = (float*)alloc((size_t)N * 4);
    int*   bucket = (int*)alloc((size_t)N * 64 * 4);
    float* P      = (float*)alloc((size_t)N * 128 * 4);
    float* full1  = (float*)alloc((size_t)N * 64 * 4);
    float* homo1  = (float*)alloc((size_t)N * 64 * 4);
    float* het1   = (float*)alloc((size_t)N * 64 * 4);
    float* Q      = P;  // P dead after spmm1; reuse for layer-2 fused features

    float* out      = (float*)d_out;
    float* outComb  = out;
    float* outHomo  = out + (size_t)N * 64;
    float* outFull  = out + (size_t)2 * N * 64;
    float* outHet   = out + (size_t)3 * N * 64;

    hipMemsetAsync(deg, 0, (size_t)N * 4, stream);
    hipMemsetAsync(cur, 0, (size_t)N * 4, stream);

    build_adj_kernel<<<(E + 255) / 256, 256, 0, stream>>>(ei, E, deg, cur, bucket);
    dinv_kernel<<<(N + 255) / 256, 256, 0, stream>>>(deg, dinv, N);

    const int nb = (N + 63) / 64;
    // Layer 1: P[:,0:64]=x@homo_W0, P[:,64:128]=x@het_W0, full1=relu(af0*x@full_W0)
    gemm_l1_kernel<<<nb, 256, 0, stream>>>(
        x, homo_W0, het_W0, full_W0, P, full1, full_a0, N);
    spmm1_kernel<<<(N + 3) / 4, 256, 0, stream>>>(
        P, bucket, cur, dinv, homo1, het1, homo_a0, het_a0, N);

    // Layer 2: Q[:,0:64]=homo1@homo_W1, Q[:,64:128]=het1@het_W1,
    //          h_full = relu(af1*full1@full_W1) written straight to d_out
    gemm_l2_kernel<<<dim3(nb, 3), 256, 0, stream>>>(
        homo1, het1, full1, homo_W1, het_W1, full_W1, Q, outFull, full_a1, N);
    spmm2_kernel<<<(N + 3) / 4, 256, 0, stream>>>(
        Q, bucket, cur, dinv, outFull, outComb, outHomo, outHet,
        homo_a1, het_a1, w_homo, w_full, w_het, N);
}

// Round 4
// 311.664 us; speedup vs baseline: 1.3006x; 1.0875x over previous
//
#include <hip/hip_runtime.h>

// ---------------------------------------------------------------------------
// DomainAlignmentModel: 3-branch GCN-ish model on MI355X.
// spmm(x) @ W == spmm(x @ W) -> project first (128->64), fuse homo+het into
// one N x 128 buffer, 1 SPMM per layer.
// R3 lesson: gemm_l1 was LDS-issue-bound (4 FMA per ds_read_b128, VALU 45%).
// R4: l1 fuses all 3 branches into one k-loop (12 FMA per ds_read);
//     l2 uses 2D register tiling (8x4 per thread) with transposed-x LDS tile.
// ---------------------------------------------------------------------------

__global__ __launch_bounds__(256) void build_adj_kernel(
    const int* __restrict__ ei, int E, int* __restrict__ deg,
    int* __restrict__ cur, int* __restrict__ bucket)
{
    int e = blockIdx.x * 256 + threadIdx.x;
    if (e >= E) return;
    int r = ei[e];          // edge_index[0][e]  (dest of the scatter-add)
    int c = ei[E + e];      // edge_index[1][e]  (source / degree node)
    atomicAdd(&deg[c], 1);
    int pos = atomicAdd(&cur[r], 1);
    if (pos < 64) bucket[(size_t)r * 64 + pos] = c;
}

__global__ __launch_bounds__(256) void dinv_kernel(
    const int* __restrict__ deg, float* __restrict__ dinv, int N)
{
    int i = blockIdx.x * 256 + threadIdx.x;
    if (i < N) dinv[i] = 1.0f / sqrtf((float)deg[i] + 1.0f);
}

// Layer 1: one block per 64-row tile; x tile (64x128, 32KB) in LDS.
// Wave w owns rows w*16..w*16+15; lane = output column. ONE k-loop computes
// homo+het+full together: each broadcast ds_read_b128 feeds 12 FMAs.
__global__ __launch_bounds__(256) void gemm_l1_kernel(
    const float* __restrict__ x,
    const float* __restrict__ wHomo, const float* __restrict__ wHet,
    const float* __restrict__ wFull,
    float* __restrict__ P, float* __restrict__ full1,
    const float* __restrict__ alphaF, int N)
{
    __shared__ float sx[64 * 128];
    const int tid = threadIdx.x;
    const int row0 = blockIdx.x * 64;

    if (row0 + 64 <= N) {
        const float4* __restrict__ src = (const float4*)(x + (size_t)row0 * 128);
        float4* dst = (float4*)sx;
        #pragma unroll
        for (int j = 0; j < 8; ++j) dst[j * 256 + tid] = src[j * 256 + tid];
    } else {
        for (int j = 0; j < 8; ++j) {
            const int idx = j * 256 + tid;        // float4 index; 32 per row
            const int row = row0 + (idx >> 5);
            float4 v = make_float4(0.f, 0.f, 0.f, 0.f);
            if (row < N) v = ((const float4*)x)[(size_t)row * 32 + (idx & 31)];
            ((float4*)sx)[idx] = v;
        }
    }
    __syncthreads();

    const int lane = tid & 63;
    const int rbase = (tid >> 6) * 16;
    const float alpha = alphaF[0];

    float aH[16], aT[16], aF[16];
    #pragma unroll
    for (int r = 0; r < 16; ++r) { aH[r] = 0.f; aT[r] = 0.f; aF[r] = 0.f; }

    #pragma unroll 1
    for (int k = 0; k < 128; k += 4) {
        const float h0 = wHomo[(k + 0) * 64 + lane];
        const float h1 = wHomo[(k + 1) * 64 + lane];
        const float h2 = wHomo[(k + 2) * 64 + lane];
        const float h3 = wHomo[(k + 3) * 64 + lane];
        const float t0 = wHet[(k + 0) * 64 + lane];
        const float t1 = wHet[(k + 1) * 64 + lane];
        const float t2 = wHet[(k + 2) * 64 + lane];
        const float t3 = wHet[(k + 3) * 64 + lane];
        const float f0 = wFull[(k + 0) * 64 + lane];
        const float f1 = wFull[(k + 1) * 64 + lane];
        const float f2 = wFull[(k + 2) * 64 + lane];
        const float f3 = wFull[(k + 3) * 64 + lane];
        #pragma unroll
        for (int r = 0; r < 16; ++r) {
            const float4 xv = *(const float4*)&sx[(rbase + r) * 128 + k];
            aH[r] = fmaf(xv.w, h3, fmaf(xv.z, h2, fmaf(xv.y, h1, fmaf(xv.x, h0, aH[r]))));
            aT[r] = fmaf(xv.w, t3, fmaf(xv.z, t2, fmaf(xv.y, t1, fmaf(xv.x, t0, aT[r]))));
            aF[r] = fmaf(xv.w, f3, fmaf(xv.z, f2, fmaf(xv.y, f1, fmaf(xv.x, f0, aF[r]))));
        }
    }
    #pragma unroll
    for (int r = 0; r < 16; ++r) {
        const int row = row0 + rbase + r;
        if (row < N) {
            P[(size_t)row * 128 + lane]      = aH[r];
            P[(size_t)row * 128 + 64 + lane] = aT[r];
            full1[(size_t)row * 64 + lane]   = fmaxf(alpha * aF[r], 0.f);
        }
    }
}

// Layer 2 (K=64): blockIdx.y = branch. 128-row tile; x staged TRANSPOSED
// (sxT[k][row], stride 129 kills bank conflicts), W staged linear. Each
// thread: 8 rows x 4 cols micro-tile -> 32 FMAs per 3 LDS reads per k.
__global__ __launch_bounds__(256) void gemm_l2_kernel(
    const float* __restrict__ in0, const float* __restrict__ in1,
    const float* __restrict__ in2,
    const float* __restrict__ w0, const float* __restrict__ w1,
    const float* __restrict__ w2,
    float* __restrict__ Q, float* __restrict__ outF,
    const float* __restrict__ alphaF, int N)
{
    __shared__ float sxT[64][129];   // [k][row], 33 KB
    __shared__ float sW[64 * 64];    // [k*64+c], 16 KB
    const int b = blockIdx.y;
    const float* __restrict__ in = (b == 0) ? in0 : ((b == 1) ? in1 : in2);
    const float* __restrict__ W  = (b == 0) ? w0  : ((b == 1) ? w1  : w2);
    const int tid = threadIdx.x;
    const int row0 = blockIdx.x * 128;

    // stage W (linear copy, layout already [k][c])
    {
        const float4* __restrict__ w4 = (const float4*)W;
        float4* sw4 = (float4*)sW;
        #pragma unroll
        for (int j = 0; j < 4; ++j) sw4[j * 256 + tid] = w4[j * 256 + tid];
    }
    // stage x transposed
    if (row0 + 128 <= N) {
        const float4* __restrict__ in4 = (const float4*)(in + (size_t)row0 * 64);
        #pragma unroll
        for (int j = 0; j < 8; ++j) {
            const int idx = j * 256 + tid;     // 0..2047
            const int row = idx >> 4;          // 16 float4 per row
            const int kc4 = idx & 15;
            const float4 v = in4[idx];
            sxT[4 * kc4 + 0][row] = v.x;
            sxT[4 * kc4 + 1][row] = v.y;
            sxT[4 * kc4 + 2][row] = v.z;
            sxT[4 * kc4 + 3][row] = v.w;
        }
    } else {
        for (int j = 0; j < 8; ++j) {
            const int idx = j * 256 + tid;
            const int row = idx >> 4;
            const int kc4 = idx & 15;
            float4 v = make_float4(0.f, 0.f, 0.f, 0.f);
            if (row0 + row < N) v = ((const float4*)in)[(size_t)(row0 + row) * 16 + kc4];
            sxT[4 * kc4 + 0][row] = v.x;
            sxT[4 * kc4 + 1][row] = v.y;
            sxT[4 * kc4 + 2][row] = v.z;
            sxT[4 * kc4 + 3][row] = v.w;
        }
    }
    __syncthreads();

    const int tx = tid & 15;    // cols 4*tx .. 4*tx+3
    const int ty = tid >> 4;    // rows 8*ty .. 8*ty+7
    float acc[8][4];
    #pragma unroll
    for (int r = 0; r < 8; ++r)
        #pragma unroll
        for (int c = 0; c < 4; ++c) acc[r][c] = 0.f;

    #pragma unroll 2
    for (int k = 0; k < 64; ++k) {
        const float4 wv = *(const float4*)&sW[k * 64 + 4 * tx];
        const float4 xa = *(const float4*)&sxT[k][8 * ty];
        const float4 xb = *(const float4*)&sxT[k][8 * ty + 4];
        const float xr[8] = { xa.x, xa.y, xa.z, xa.w, xb.x, xb.y, xb.z, xb.w };
        #pragma unroll
        for (int r = 0; r < 8; ++r) {
            acc[r][0] = fmaf(xr[r], wv.x, acc[r][0]);
            acc[r][1] = fmaf(xr[r], wv.y, acc[r][1]);
            acc[r][2] = fmaf(xr[r], wv.z, acc[r][2]);
            acc[r][3] = fmaf(xr[r], wv.w, acc[r][3]);
        }
    }

    const float alpha = alphaF[0];
    #pragma unroll
    for (int r = 0; r < 8; ++r) {
        const int row = row0 + 8 * ty + r;
        if (row < N) {
            if (b < 2) {
                float4 o = make_float4(acc[r][0], acc[r][1], acc[r][2], acc[r][3]);
                ((float4*)Q)[(size_t)row * 32 + b * 16 + tx] = o;
            } else {
                float4 o = make_float4(fmaxf(alpha * acc[r][0], 0.f),
                                       fmaxf(alpha * acc[r][1], 0.f),
                                       fmaxf(alpha * acc[r][2], 0.f),
                                       fmaxf(alpha * acc[r][3], 0.f));
                ((float4*)outF)[(size_t)row * 16 + tx] = o;
            }
        }
    }
}

// SPMM over fused N x 128 features. One wave per dest node; lane holds
// features (2*lane, 2*lane+1) as float2. Lanes 0-31 -> homo half, 32-63 -> het.
__global__ __launch_bounds__(256) void spmm1_kernel(
    const float* __restrict__ P, const int* __restrict__ bucket, const int* __restrict__ cnt,
    const float* __restrict__ dinv, float* __restrict__ homo1, float* __restrict__ het1,
    const float* __restrict__ aH, const float* __restrict__ aT, int N)
{
    const int i = blockIdx.x * 4 + (threadIdx.x >> 6);
    if (i >= N) return;
    const int lane = threadIdx.x & 63;
    const float2* __restrict__ P2 = (const float2*)P;
    const float di = dinv[i];
    const float2 ps = P2[(size_t)i * 64 + lane];
    int n = cnt[i]; if (n > 64) n = 64;
    const int* __restrict__ brow = bucket + (size_t)i * 64;
    float ax = 0.f, ay = 0.f;
    for (int k0 = 0; k0 < n; k0 += 8) {
        #pragma unroll
        for (int j = 0; j < 8; ++j) {
            const int k = k0 + j;
            const bool act = (k < n);
            const int c = act ? brow[k] : i;       // broadcast load (uniform)
            const float dc = act ? dinv[c] : 0.f;  // broadcast gather
            const float2 v = P2[(size_t)c * 64 + lane];
            ax += dc * v.x; ay += dc * v.y;
        }
    }
    const float yx = di * (ax + di * ps.x);
    const float yy = di * (ay + di * ps.y);
    float ox, oy; float* dst;
    if (lane < 32) {
        const float a = aH[0];
        ox = fmaxf(a * yx, 0.f); oy = fmaxf(a * yy, 0.f);
        dst = homo1 + (size_t)i * 64 + 2 * lane;
    } else {
        const float a = aT[0];
        ox = fmaxf(a * (ps.x - yx), 0.f); oy = fmaxf(a * (ps.y - yy), 0.f);
        dst = het1 + (size_t)i * 64 + 2 * (lane - 32);
    }
    *(float2*)dst = make_float2(ox, oy);
}

__global__ __launch_bounds__(256) void spmm2_kernel(
    const float* __restrict__ Q, const int* __restrict__ bucket, const int* __restrict__ cnt,
    const float* __restrict__ dinv, const float* __restrict__ full2,
    float* __restrict__ outComb, float* __restrict__ outHomo, float* __restrict__ outHet,
    const float* __restrict__ aH, const float* __restrict__ aT,
    const float* __restrict__ wH, const float* __restrict__ wF, const float* __restrict__ wT,
    int N)
{
    const int i = blockIdx.x * 4 + (threadIdx.x >> 6);
    if (i >= N) return;
    const int lane = threadIdx.x & 63;
    const float2* __restrict__ Q2 = (const float2*)Q;
    const float di = dinv[i];
    const float2 qs = Q2[(size_t)i * 64 + lane];
    int n = cnt[i]; if (n > 64) n = 64;
    const int* __restrict__ brow = bucket + (size_t)i * 64;
    float ax = 0.f, ay = 0.f;
    for (int k0 = 0; k0 < n; k0 += 8) {
        #pragma unroll
        for (int j = 0; j < 8; ++j) {
            const int k = k0 + j;
            const bool act = (k < n);
            const int c = act ? brow[k] : i;
            const float dc = act ? dinv[c] : 0.f;
            const float2 v = Q2[(size_t)c * 64 + lane];
            ax += dc * v.x; ay += dc * v.y;
        }
    }
    const float yx = di * (ax + di * qs.x);
    const float yy = di * (ay + di * qs.y);
    float vx, vy; float* dst;
    if (lane < 32) {
        const float a = aH[0];
        vx = fmaxf(a * yx, 0.f); vy = fmaxf(a * yy, 0.f);
        dst = outHomo + (size_t)i * 64 + 2 * lane;
    } else {
        const float a = aT[0];
        vx = fmaxf(a * (qs.x - yx), 0.f); vy = fmaxf(a * (qs.y - yy), 0.f);
        dst = outHet + (size_t)i * 64 + 2 * (lane - 32);
    }
    *(float2*)dst = make_float2(vx, vy);
    // combined = wH*h_homo + wF*h_full + wT*h_het; exchange halves across lane^32
    const float tx = __shfl_xor(vx, 32);
    const float ty = __shfl_xor(vy, 32);
    if (lane < 32) {
        const float2 f2 = ((const float2*)full2)[(size_t)i * 32 + lane];
        const float cwh = wH[0], cwf = wF[0], cwt = wT[0];
        const float cx = cwh * vx + cwf * f2.x + cwt * tx;
        const float cy = cwh * vy + cwf * f2.y + cwt * ty;
        *(float2*)(outComb + (size_t)i * 64 + 2 * lane) = make_float2(cx, cy);
    }
}

extern "C" void kernel_launch(void* const* d_in, const int* in_sizes, int n_in,
                              void* d_out, int out_size, void* d_ws, size_t ws_size,
                              hipStream_t stream)
{
    const float* x  = (const float*)d_in[0];
    const int*   ei = (const int*)d_in[1];
    const int N = in_sizes[0] / 128;
    const int E = in_sizes[1] / 2;
    const float* homo_W0 = (const float*)d_in[3];
    const float* homo_W1 = (const float*)d_in[4];
    const float* full_W0 = (const float*)d_in[5];
    const float* full_W1 = (const float*)d_in[6];
    const float* het_W0  = (const float*)d_in[7];
    const float* het_W1  = (const float*)d_in[8];
    const float* homo_a0 = (const float*)d_in[9];
    const float* homo_a1 = (const float*)d_in[10];
    const float* full_a0 = (const float*)d_in[11];
    const float* full_a1 = (const float*)d_in[12];
    const float* het_a0  = (const float*)d_in[13];
    const float* het_a1  = (const float*)d_in[14];
    const float* w_homo  = (const float*)d_in[15];
    const float* w_full  = (const float*)d_in[16];
    const float* w_het   = (const float*)d_in[17];

    char* ws = (char*)d_ws;
    size_t off = 0;
    auto alloc = [&](size_t bytes) -> char* {
        char* p = ws + off;
        off = (off + bytes + 511) & ~(size_t)511;
        return p;
    };
    int*   deg    = (int*)alloc((size_t)N * 4);
    int*   cur    = (int*)alloc((size_t)N * 4);
    float* dinv   = (float*)alloc((size_t)N * 4);
    int*   bucket = (int*)alloc((size_t)N * 64 * 4);
    float* P      = (float*)alloc((size_t)N * 128 * 4);
    float* full1  = (float*)alloc((size_t)N * 64 * 4);
    float* homo1  = (float*)alloc((size_t)N * 64 * 4);
    float* het1   = (float*)alloc((size_t)N * 64 * 4);
    float* Q      = P;  // P dead after spmm1; reuse for layer-2 fused features

    float* out      = (float*)d_out;
    float* outComb  = out;
    float* outHomo  = out + (size_t)N * 64;
    float* outFull  = out + (size_t)2 * N * 64;
    float* outHet   = out + (size_t)3 * N * 64;

    hipMemsetAsync(deg, 0, (size_t)N * 4, stream);
    hipMemsetAsync(cur, 0, (size_t)N * 4, stream);

    build_adj_kernel<<<(E + 255) / 256, 256, 0, stream>>>(ei, E, deg, cur, bucket);
    dinv_kernel<<<(N + 255) / 256, 256, 0, stream>>>(deg, dinv, N);

    // Layer 1: P[:,0:64]=x@homo_W0, P[:,64:128]=x@het_W0, full1=relu(af0*x@full_W0)
    gemm_l1_kernel<<<(N + 63) / 64, 256, 0, stream>>>(
        x, homo_W0, het_W0, full_W0, P, full1, full_a0, N);
    spmm1_kernel<<<(N + 3) / 4, 256, 0, stream>>>(
        P, bucket, cur, dinv, homo1, het1, homo_a0, het_a0, N);

    // Layer 2: Q[:,0:64]=homo1@homo_W1, Q[:,64:128]=het1@het_W1,
    //          h_full = relu(af1*full1@full_W1) written straight to d_out
    gemm_l2_kernel<<<dim3((N + 127) / 128, 3), 256, 0, stream>>>(
        homo1, het1, full1, homo_W1, het_W1, full_W1, Q, outFull, full_a1, N);
    spmm2_kernel<<<(N + 3) / 4, 256, 0, stream>>>(
        Q, bucket, cur, dinv, outFull, outComb, outHomo, outHet,
        homo_a1, het_a1, w_homo, w_full, w_het, N);
}

// Round 5
// 289.934 us; speedup vs baseline: 1.3981x; 1.0749x over previous
//
#include <hip/hip_runtime.h>

// ---------------------------------------------------------------------------
// DomainAlignmentModel: 3-branch GCN-ish model on MI355X.
// spmm(x) @ W == spmm(x @ W) -> project first (128->64), fuse homo+het into
// one N x 128 buffer, 1 SPMM per layer.
// R4 lesson: build_adj was write-allocate-thrash-bound (73MB HBM writes for a
// 12.8MB bucket). R5: bucket -> u16 (halves scatter footprint), 4 edges/thread;
// SPMM gather buffers P/Q stored as bf16 pairs (halves ~410MB/spmm gather).
// ---------------------------------------------------------------------------

static __device__ __forceinline__ unsigned short f2bf(float f) {
    unsigned int u = __float_as_uint(f);
    u += 0x7FFFu + ((u >> 16) & 1u);   // round-to-nearest-even
    return (unsigned short)(u >> 16);
}
static __device__ __forceinline__ float bflo(unsigned int pv) {
    return __uint_as_float(pv << 16);
}
static __device__ __forceinline__ float bfhi(unsigned int pv) {
    return __uint_as_float(pv & 0xFFFF0000u);
}

__global__ __launch_bounds__(256) void build_adj_kernel(
    const int* __restrict__ ei, int E, int* __restrict__ deg,
    int* __restrict__ cur, unsigned short* __restrict__ bucket)
{
    const int base = (blockIdx.x * 256 + threadIdx.x) * 4;
    if (base >= E) return;
    if (base + 4 <= E) {
        const int4 r4 = *(const int4*)(ei + base);
        const int4 c4 = *(const int4*)(ei + E + base);
        atomicAdd(&deg[c4.x], 1); atomicAdd(&deg[c4.y], 1);
        atomicAdd(&deg[c4.z], 1); atomicAdd(&deg[c4.w], 1);
        int p0 = atomicAdd(&cur[r4.x], 1);
        int p1 = atomicAdd(&cur[r4.y], 1);
        int p2 = atomicAdd(&cur[r4.z], 1);
        int p3 = atomicAdd(&cur[r4.w], 1);
        if (p0 < 64) bucket[(size_t)r4.x * 64 + p0] = (unsigned short)c4.x;
        if (p1 < 64) bucket[(size_t)r4.y * 64 + p1] = (unsigned short)c4.y;
        if (p2 < 64) bucket[(size_t)r4.z * 64 + p2] = (unsigned short)c4.z;
        if (p3 < 64) bucket[(size_t)r4.w * 64 + p3] = (unsigned short)c4.w;
    } else {
        for (int e = base; e < E; ++e) {
            int r = ei[e], c = ei[E + e];
            atomicAdd(&deg[c], 1);
            int pos = atomicAdd(&cur[r], 1);
            if (pos < 64) bucket[(size_t)r * 64 + pos] = (unsigned short)c;
        }
    }
}

__global__ __launch_bounds__(256) void dinv_kernel(
    const int* __restrict__ deg, float* __restrict__ dinv, int N)
{
    int i = blockIdx.x * 256 + threadIdx.x;
    if (i < N) dinv[i] = 1.0f / sqrtf((float)deg[i] + 1.0f);
}

// Layer 1: one block per 64-row tile; x tile (64x128, 32KB) in LDS.
// Wave w owns rows w*16..w*16+15; lane = output column. ONE k-loop computes
// homo+het+full together: each broadcast ds_read_b128 feeds 12 FMAs.
// P written as bf16 (u16 per element).
__global__ __launch_bounds__(256) void gemm_l1_kernel(
    const float* __restrict__ x,
    const float* __restrict__ wHomo, const float* __restrict__ wHet,
    const float* __restrict__ wFull,
    unsigned short* __restrict__ Pb, float* __restrict__ full1,
    const float* __restrict__ alphaF, int N)
{
    __shared__ float sx[64 * 128];
    const int tid = threadIdx.x;
    const int row0 = blockIdx.x * 64;

    if (row0 + 64 <= N) {
        const float4* __restrict__ src = (const float4*)(x + (size_t)row0 * 128);
        float4* dst = (float4*)sx;
        #pragma unroll
        for (int j = 0; j < 8; ++j) dst[j * 256 + tid] = src[j * 256 + tid];
    } else {
        for (int j = 0; j < 8; ++j) {
            const int idx = j * 256 + tid;        // float4 index; 32 per row
            const int row = row0 + (idx >> 5);
            float4 v = make_float4(0.f, 0.f, 0.f, 0.f);
            if (row < N) v = ((const float4*)x)[(size_t)row * 32 + (idx & 31)];
            ((float4*)sx)[idx] = v;
        }
    }
    __syncthreads();

    const int lane = tid & 63;
    const int rbase = (tid >> 6) * 16;
    const float alpha = alphaF[0];

    float aH[16], aT[16], aF[16];
    #pragma unroll
    for (int r = 0; r < 16; ++r) { aH[r] = 0.f; aT[r] = 0.f; aF[r] = 0.f; }

    #pragma unroll 1
    for (int k = 0; k < 128; k += 4) {
        const float h0 = wHomo[(k + 0) * 64 + lane];
        const float h1 = wHomo[(k + 1) * 64 + lane];
        const float h2 = wHomo[(k + 2) * 64 + lane];
        const float h3 = wHomo[(k + 3) * 64 + lane];
        const float t0 = wHet[(k + 0) * 64 + lane];
        const float t1 = wHet[(k + 1) * 64 + lane];
        const float t2 = wHet[(k + 2) * 64 + lane];
        const float t3 = wHet[(k + 3) * 64 + lane];
        const float f0 = wFull[(k + 0) * 64 + lane];
        const float f1 = wFull[(k + 1) * 64 + lane];
        const float f2 = wFull[(k + 2) * 64 + lane];
        const float f3 = wFull[(k + 3) * 64 + lane];
        #pragma unroll
        for (int r = 0; r < 16; ++r) {
            const float4 xv = *(const float4*)&sx[(rbase + r) * 128 + k];
            aH[r] = fmaf(xv.w, h3, fmaf(xv.z, h2, fmaf(xv.y, h1, fmaf(xv.x, h0, aH[r]))));
            aT[r] = fmaf(xv.w, t3, fmaf(xv.z, t2, fmaf(xv.y, t1, fmaf(xv.x, t0, aT[r]))));
            aF[r] = fmaf(xv.w, f3, fmaf(xv.z, f2, fmaf(xv.y, f1, fmaf(xv.x, f0, aF[r]))));
        }
    }
    #pragma unroll
    for (int r = 0; r < 16; ++r) {
        const int row = row0 + rbase + r;
        if (row < N) {
            Pb[(size_t)row * 128 + lane]      = f2bf(aH[r]);
            Pb[(size_t)row * 128 + 64 + lane] = f2bf(aT[r]);
            full1[(size_t)row * 64 + lane]    = fmaxf(alpha * aF[r], 0.f);
        }
    }
}

// Layer 2 (K=64): blockIdx.y = branch. 128-row tile; x staged TRANSPOSED
// (sxT[k][row], stride 129), W staged linear. 8x4 micro-tile per thread.
// Q (branches 0,1) written bf16; full branch written fp32 to d_out.
__global__ __launch_bounds__(256) void gemm_l2_kernel(
    const float* __restrict__ in0, const float* __restrict__ in1,
    const float* __restrict__ in2,
    const float* __restrict__ w0, const float* __restrict__ w1,
    const float* __restrict__ w2,
    unsigned short* __restrict__ Qb, float* __restrict__ outF,
    const float* __restrict__ alphaF, int N)
{
    __shared__ float sxT[64][129];   // [k][row], 33 KB
    __shared__ float sW[64 * 64];    // [k*64+c], 16 KB
    const int b = blockIdx.y;
    const float* __restrict__ in = (b == 0) ? in0 : ((b == 1) ? in1 : in2);
    const float* __restrict__ W  = (b == 0) ? w0  : ((b == 1) ? w1  : w2);
    const int tid = threadIdx.x;
    const int row0 = blockIdx.x * 128;

    {
        const float4* __restrict__ w4 = (const float4*)W;
        float4* sw4 = (float4*)sW;
        #pragma unroll
        for (int j = 0; j < 4; ++j) sw4[j * 256 + tid] = w4[j * 256 + tid];
    }
    if (row0 + 128 <= N) {
        const float4* __restrict__ in4 = (const float4*)(in + (size_t)row0 * 64);
        #pragma unroll
        for (int j = 0; j < 8; ++j) {
            const int idx = j * 256 + tid;     // 0..2047
            const int row = idx >> 4;          // 16 float4 per row
            const int kc4 = idx & 15;
            const float4 v = in4[idx];
            sxT[4 * kc4 + 0][row] = v.x;
            sxT[4 * kc4 + 1][row] = v.y;
            sxT[4 * kc4 + 2][row] = v.z;
            sxT[4 * kc4 + 3][row] = v.w;
        }
    } else {
        for (int j = 0; j < 8; ++j) {
            const int idx = j * 256 + tid;
            const int row = idx >> 4;
            const int kc4 = idx & 15;
            float4 v = make_float4(0.f, 0.f, 0.f, 0.f);
            if (row0 + row < N) v = ((const float4*)in)[(size_t)(row0 + row) * 16 + kc4];
            sxT[4 * kc4 + 0][row] = v.x;
            sxT[4 * kc4 + 1][row] = v.y;
            sxT[4 * kc4 + 2][row] = v.z;
            sxT[4 * kc4 + 3][row] = v.w;
        }
    }
    __syncthreads();

    const int tx = tid & 15;    // cols 4*tx .. 4*tx+3
    const int ty = tid >> 4;    // rows 8*ty .. 8*ty+7
    float acc[8][4];
    #pragma unroll
    for (int r = 0; r < 8; ++r)
        #pragma unroll
        for (int c = 0; c < 4; ++c) acc[r][c] = 0.f;

    #pragma unroll 2
    for (int k = 0; k < 64; ++k) {
        const float4 wv = *(const float4*)&sW[k * 64 + 4 * tx];
        const float4 xa = *(const float4*)&sxT[k][8 * ty];
        const float4 xb = *(const float4*)&sxT[k][8 * ty + 4];
        const float xr[8] = { xa.x, xa.y, xa.z, xa.w, xb.x, xb.y, xb.z, xb.w };
        #pragma unroll
        for (int r = 0; r < 8; ++r) {
            acc[r][0] = fmaf(xr[r], wv.x, acc[r][0]);
            acc[r][1] = fmaf(xr[r], wv.y, acc[r][1]);
            acc[r][2] = fmaf(xr[r], wv.z, acc[r][2]);
            acc[r][3] = fmaf(xr[r], wv.w, acc[r][3]);
        }
    }

    const float alpha = alphaF[0];
    #pragma unroll
    for (int r = 0; r < 8; ++r) {
        const int row = row0 + 8 * ty + r;
        if (row < N) {
            if (b < 2) {
                uint2 o;
                o.x = (unsigned int)f2bf(acc[r][0]) | ((unsigned int)f2bf(acc[r][1]) << 16);
                o.y = (unsigned int)f2bf(acc[r][2]) | ((unsigned int)f2bf(acc[r][3]) << 16);
                ((uint2*)Qb)[(size_t)row * 32 + b * 16 + tx] = o;
            } else {
                float4 o = make_float4(fmaxf(alpha * acc[r][0], 0.f),
                                       fmaxf(alpha * acc[r][1], 0.f),
                                       fmaxf(alpha * acc[r][2], 0.f),
                                       fmaxf(alpha * acc[r][3], 0.f));
                ((float4*)outF)[(size_t)row * 16 + tx] = o;
            }
        }
    }
}

// SPMM over fused N x 128 bf16 features. One wave per dest node; lane holds
// features (2*lane, 2*lane+1) as one u32. Lanes 0-31 -> homo, 32-63 -> het.
__global__ __launch_bounds__(256) void spmm1_kernel(
    const unsigned short* __restrict__ Pb, const unsigned short* __restrict__ bucket,
    const int* __restrict__ cnt, const float* __restrict__ dinv,
    float* __restrict__ homo1, float* __restrict__ het1,
    const float* __restrict__ aH, const float* __restrict__ aT, int N)
{
    const int i = blockIdx.x * 4 + (threadIdx.x >> 6);
    if (i >= N) return;
    const int lane = threadIdx.x & 63;
    const unsigned int* __restrict__ P4 = (const unsigned int*)Pb;
    const float di = dinv[i];
    const unsigned int pself = P4[(size_t)i * 64 + lane];
    const float psx = bflo(pself), psy = bfhi(pself);
    int n = cnt[i]; if (n > 64) n = 64;
    const unsigned short* __restrict__ brow = bucket + (size_t)i * 64;
    float ax = 0.f, ay = 0.f;
    for (int k0 = 0; k0 < n; k0 += 8) {
        #pragma unroll
        for (int j = 0; j < 8; ++j) {
            const int k = k0 + j;
            const bool act = (k < n);
            const int c = act ? (int)brow[k] : i;  // broadcast load (uniform)
            const float dc = act ? dinv[c] : 0.f;  // broadcast gather
            const unsigned int pv = P4[(size_t)c * 64 + lane];
            ax = fmaf(dc, bflo(pv), ax);
            ay = fmaf(dc, bfhi(pv), ay);
        }
    }
    const float yx = di * (ax + di * psx);
    const float yy = di * (ay + di * psy);
    float ox, oy; float* dst;
    if (lane < 32) {
        const float a = aH[0];
        ox = fmaxf(a * yx, 0.f); oy = fmaxf(a * yy, 0.f);
        dst = homo1 + (size_t)i * 64 + 2 * lane;
    } else {
        const float a = aT[0];
        ox = fmaxf(a * (psx - yx), 0.f); oy = fmaxf(a * (psy - yy), 0.f);
        dst = het1 + (size_t)i * 64 + 2 * (lane - 32);
    }
    *(float2*)dst = make_float2(ox, oy);
}

__global__ __launch_bounds__(256) void spmm2_kernel(
    const unsigned short* __restrict__ Qb, const unsigned short* __restrict__ bucket,
    const int* __restrict__ cnt, const float* __restrict__ dinv,
    const float* __restrict__ full2,
    float* __restrict__ outComb, float* __restrict__ outHomo, float* __restrict__ outHet,
    const float* __restrict__ aH, const float* __restrict__ aT,
    const float* __restrict__ wH, const float* __restrict__ wF, const float* __restrict__ wT,
    int N)
{
    const int i = blockIdx.x * 4 + (threadIdx.x >> 6);
    if (i >= N) return;
    const int lane = threadIdx.x & 63;
    const unsigned int* __restrict__ Q4 = (const unsigned int*)Qb;
    const float di = dinv[i];
    const unsigned int qself = Q4[(size_t)i * 64 + lane];
    const float qsx = bflo(qself), qsy = bfhi(qself);
    int n = cnt[i]; if (n > 64) n = 64;
    const unsigned short* __restrict__ brow = bucket + (size_t)i * 64;
    float ax = 0.f, ay = 0.f;
    for (int k0 = 0; k0 < n; k0 += 8) {
        #pragma unroll
        for (int j = 0; j < 8; ++j) {
            const int k = k0 + j;
            const bool act = (k < n);
            const int c = act ? (int)brow[k] : i;
            const float dc = act ? dinv[c] : 0.f;
            const unsigned int qv = Q4[(size_t)c * 64 + lane];
            ax = fmaf(dc, bflo(qv), ax);
            ay = fmaf(dc, bfhi(qv), ay);
        }
    }
    const float yx = di * (ax + di * qsx);
    const float yy = di * (ay + di * qsy);
    float vx, vy; float* dst;
    if (lane < 32) {
        const float a = aH[0];
        vx = fmaxf(a * yx, 0.f); vy = fmaxf(a * yy, 0.f);
        dst = outHomo + (size_t)i * 64 + 2 * lane;
    } else {
        const float a = aT[0];
        vx = fmaxf(a * (qsx - yx), 0.f); vy = fmaxf(a * (qsy - yy), 0.f);
        dst = outHet + (size_t)i * 64 + 2 * (lane - 32);
    }
    *(float2*)dst = make_float2(vx, vy);
    // combined = wH*h_homo + wF*h_full + wT*h_het; exchange halves across lane^32
    const float tx = __shfl_xor(vx, 32);
    const float ty = __shfl_xor(vy, 32);
    if (lane < 32) {
        const float2 f2 = ((const float2*)full2)[(size_t)i * 32 + lane];
        const float cwh = wH[0], cwf = wF[0], cwt = wT[0];
        const float cx = cwh * vx + cwf * f2.x + cwt * tx;
        const float cy = cwh * vy + cwf * f2.y + cwt * ty;
        *(float2*)(outComb + (size_t)i * 64 + 2 * lane) = make_float2(cx, cy);
    }
}

extern "C" void kernel_launch(void* const* d_in, const int* in_sizes, int n_in,
                              void* d_out, int out_size, void* d_ws, size_t ws_size,
                              hipStream_t stream)
{
    const float* x  = (const float*)d_in[0];
    const int*   ei = (const int*)d_in[1];
    const int N = in_sizes[0] / 128;
    const int E = in_sizes[1] / 2;
    const float* homo_W0 = (const float*)d_in[3];
    const float* homo_W1 = (const float*)d_in[4];
    const float* full_W0 = (const float*)d_in[5];
    const float* full_W1 = (const float*)d_in[6];
    const float* het_W0  = (const float*)d_in[7];
    const float* het_W1  = (const float*)d_in[8];
    const float* homo_a0 = (const float*)d_in[9];
    const float* homo_a1 = (const float*)d_in[10];
    const float* full_a0 = (const float*)d_in[11];
    const float* full_a1 = (const float*)d_in[12];
    const float* het_a0  = (const float*)d_in[13];
    const float* het_a1  = (const float*)d_in[14];
    const float* w_homo  = (const float*)d_in[15];
    const float* w_full  = (const float*)d_in[16];
    const float* w_het   = (const float*)d_in[17];

    char* ws = (char*)d_ws;
    size_t off = 0;
    auto alloc = [&](size_t bytes) -> char* {
        char* p = ws + off;
        off = (off + bytes + 511) & ~(size_t)511;
        return p;
    };
    int*            deg    = (int*)alloc((size_t)N * 4);
    int*            cur    = (int*)alloc((size_t)N * 4);
    float*          dinv   = (float*)alloc((size_t)N * 4);
    unsigned short* bucket = (unsigned short*)alloc((size_t)N * 64 * 2);
    unsigned short* Pb     = (unsigned short*)alloc((size_t)N * 128 * 2);
    float*          full1  = (float*)alloc((size_t)N * 64 * 4);
    float*          homo1  = (float*)alloc((size_t)N * 64 * 4);
    float*          het1   = (float*)alloc((size_t)N * 64 * 4);
    unsigned short* Qb     = Pb;  // Pb dead after spmm1; reuse for layer 2

    float* out      = (float*)d_out;
    float* outComb  = out;
    float* outHomo  = out + (size_t)N * 64;
    float* outFull  = out + (size_t)2 * N * 64;
    float* outHet   = out + (size_t)3 * N * 64;

    hipMemsetAsync(deg, 0, (size_t)N * 4, stream);
    hipMemsetAsync(cur, 0, (size_t)N * 4, stream);

    build_adj_kernel<<<(E / 4 + 255) / 256, 256, 0, stream>>>(ei, E, deg, cur, bucket);
    dinv_kernel<<<(N + 255) / 256, 256, 0, stream>>>(deg, dinv, N);

    // Layer 1: Pb[:,0:64]=x@homo_W0, Pb[:,64:128]=x@het_W0 (bf16),
    //          full1=relu(af0*x@full_W0)
    gemm_l1_kernel<<<(N + 63) / 64, 256, 0, stream>>>(
        x, homo_W0, het_W0, full_W0, Pb, full1, full_a0, N);
    spmm1_kernel<<<(N + 3) / 4, 256, 0, stream>>>(
        Pb, bucket, cur, dinv, homo1, het1, homo_a0, het_a0, N);

    // Layer 2: Qb[:,0:64]=homo1@homo_W1, Qb[:,64:128]=het1@het_W1 (bf16),
    //          h_full = relu(af1*full1@full_W1) written straight to d_out
    gemm_l2_kernel<<<dim3((N + 127) / 128, 3), 256, 0, stream>>>(
        homo1, het1, full1, homo_W1, het_W1, full_W1, Qb, outFull, full_a1, N);
    spmm2_kernel<<<(N + 3) / 4, 256, 0, stream>>>(
        Qb, bucket, cur, dinv, outFull, outComb, outHomo, outHet,
        homo_a1, het_a1, w_homo, w_full, w_het, N);
}

// Round 6
// 279.290 us; speedup vs baseline: 1.4513x; 1.0381x over previous
//
#include <hip/hip_runtime.h>

// ---------------------------------------------------------------------------
// DomainAlignmentModel: 3-branch GCN-ish model on MI355X.
// spmm(x) @ W == spmm(x @ W) -> project first (128->64), fuse homo+het into
// one N x 128 buffer, 1 SPMM per layer. P/Q gather buffers in bf16.
// R5 lesson: build_adj WRITE_SIZE (69MB) was cross-XCD line replication +
// atomic writebacks, not scatter footprint (u16 barely moved it).
// R6: XCD-partitioned build — blockIdx&7 selects a dest/src-row partition;
// each bucket/deg/cur line is written by exactly one XCD, slice fits its L2.
// Edge list read 8x (7 from L3). Correctness is XCD-mapping-independent.
// ---------------------------------------------------------------------------

static __device__ __forceinline__ unsigned short f2bf(float f) {
    unsigned int u = __float_as_uint(f);
    u += 0x7FFFu + ((u >> 16) & 1u);   // round-to-nearest-even
    return (unsigned short)(u >> 16);
}
static __device__ __forceinline__ float bflo(unsigned int pv) {
    return __uint_as_float(pv << 16);
}
static __device__ __forceinline__ float bfhi(unsigned int pv) {
    return __uint_as_float(pv & 0xFFFF0000u);
}

#define EDGES_PER_BLOCK 4096   // 256 threads * 16 edges

__global__ __launch_bounds__(256) void build_adj_kernel(
    const int* __restrict__ ei, int E, int lopart_size,
    int* __restrict__ deg, int* __restrict__ cur,
    unsigned short* __restrict__ bucket)
{
    const int part  = blockIdx.x & 7;
    const int chunk = blockIdx.x >> 3;
    const int lo = part * lopart_size;
    const int hi = lo + lopart_size;
    const int base = chunk * EDGES_PER_BLOCK + threadIdx.x * 4;

    #pragma unroll 1
    for (int j = 0; j < 4; ++j) {
        const int e = base + j * 1024;          // 256 threads * 4 edges
        if (e + 4 <= E) {
            const int4 r4 = *(const int4*)(ei + e);
            const int4 c4 = *(const int4*)(ei + E + e);
            const int rr[4] = { r4.x, r4.y, r4.z, r4.w };
            const int cc[4] = { c4.x, c4.y, c4.z, c4.w };
            #pragma unroll
            for (int t = 0; t < 4; ++t) {
                if (cc[t] >= lo && cc[t] < hi) atomicAdd(&deg[cc[t]], 1);
                if (rr[t] >= lo && rr[t] < hi) {
                    const int pos = atomicAdd(&cur[rr[t]], 1);
                    if (pos < 64)
                        bucket[(size_t)rr[t] * 64 + pos] = (unsigned short)cc[t];
                }
            }
        } else {
            for (int q = e; q < E; ++q) {
                const int r = ei[q], c = ei[E + q];
                if (c >= lo && c < hi) atomicAdd(&deg[c], 1);
                if (r >= lo && r < hi) {
                    const int pos = atomicAdd(&cur[r], 1);
                    if (pos < 64) bucket[(size_t)r * 64 + pos] = (unsigned short)c;
                }
            }
        }
    }
}

__global__ __launch_bounds__(256) void dinv_kernel(
    const int* __restrict__ deg, float* __restrict__ dinv, int N)
{
    int i = blockIdx.x * 256 + threadIdx.x;
    if (i < N) dinv[i] = 1.0f / sqrtf((float)deg[i] + 1.0f);
}

// Layer 1: one block per 64-row tile; x tile (64x128, 32KB) in LDS.
// Wave w owns rows w*16..w*16+15; lane = output column. ONE k-loop computes
// homo+het+full together: each broadcast ds_read_b128 feeds 12 FMAs.
// P written as bf16 (u16 per element).
__global__ __launch_bounds__(256) void gemm_l1_kernel(
    const float* __restrict__ x,
    const float* __restrict__ wHomo, const float* __restrict__ wHet,
    const float* __restrict__ wFull,
    unsigned short* __restrict__ Pb, float* __restrict__ full1,
    const float* __restrict__ alphaF, int N)
{
    __shared__ float sx[64 * 128];
    const int tid = threadIdx.x;
    const int row0 = blockIdx.x * 64;

    if (row0 + 64 <= N) {
        const float4* __restrict__ src = (const float4*)(x + (size_t)row0 * 128);
        float4* dst = (float4*)sx;
        #pragma unroll
        for (int j = 0; j < 8; ++j) dst[j * 256 + tid] = src[j * 256 + tid];
    } else {
        for (int j = 0; j < 8; ++j) {
            const int idx = j * 256 + tid;        // float4 index; 32 per row
            const int row = row0 + (idx >> 5);
            float4 v = make_float4(0.f, 0.f, 0.f, 0.f);
            if (row < N) v = ((const float4*)x)[(size_t)row * 32 + (idx & 31)];
            ((float4*)sx)[idx] = v;
        }
    }
    __syncthreads();

    const int lane = tid & 63;
    const int rbase = (tid >> 6) * 16;
    const float alpha = alphaF[0];

    float aH[16], aT[16], aF[16];
    #pragma unroll
    for (int r = 0; r < 16; ++r) { aH[r] = 0.f; aT[r] = 0.f; aF[r] = 0.f; }

    #pragma unroll 1
    for (int k = 0; k < 128; k += 4) {
        const float h0 = wHomo[(k + 0) * 64 + lane];
        const float h1 = wHomo[(k + 1) * 64 + lane];
        const float h2 = wHomo[(k + 2) * 64 + lane];
        const float h3 = wHomo[(k + 3) * 64 + lane];
        const float t0 = wHet[(k + 0) * 64 + lane];
        const float t1 = wHet[(k + 1) * 64 + lane];
        const float t2 = wHet[(k + 2) * 64 + lane];
        const float t3 = wHet[(k + 3) * 64 + lane];
        const float f0 = wFull[(k + 0) * 64 + lane];
        const float f1 = wFull[(k + 1) * 64 + lane];
        const float f2 = wFull[(k + 2) * 64 + lane];
        const float f3 = wFull[(k + 3) * 64 + lane];
        #pragma unroll
        for (int r = 0; r < 16; ++r) {
            const float4 xv = *(const float4*)&sx[(rbase + r) * 128 + k];
            aH[r] = fmaf(xv.w, h3, fmaf(xv.z, h2, fmaf(xv.y, h1, fmaf(xv.x, h0, aH[r]))));
            aT[r] = fmaf(xv.w, t3, fmaf(xv.z, t2, fmaf(xv.y, t1, fmaf(xv.x, t0, aT[r]))));
            aF[r] = fmaf(xv.w, f3, fmaf(xv.z, f2, fmaf(xv.y, f1, fmaf(xv.x, f0, aF[r]))));
        }
    }
    #pragma unroll
    for (int r = 0; r < 16; ++r) {
        const int row = row0 + rbase + r;
        if (row < N) {
            Pb[(size_t)row * 128 + lane]      = f2bf(aH[r]);
            Pb[(size_t)row * 128 + 64 + lane] = f2bf(aT[r]);
            full1[(size_t)row * 64 + lane]    = fmaxf(alpha * aF[r], 0.f);
        }
    }
}

// Layer 2 (K=64): blockIdx.y = branch. 128-row tile; x staged TRANSPOSED
// (sxT[k][row], stride 129), W staged linear. 8x4 micro-tile per thread.
// Q (branches 0,1) written bf16; full branch written fp32 to d_out.
__global__ __launch_bounds__(256) void gemm_l2_kernel(
    const float* __restrict__ in0, const float* __restrict__ in1,
    const float* __restrict__ in2,
    const float* __restrict__ w0, const float* __restrict__ w1,
    const float* __restrict__ w2,
    unsigned short* __restrict__ Qb, float* __restrict__ outF,
    const float* __restrict__ alphaF, int N)
{
    __shared__ float sxT[64][129];   // [k][row], 33 KB
    __shared__ float sW[64 * 64];    // [k*64+c], 16 KB
    const int b = blockIdx.y;
    const float* __restrict__ in = (b == 0) ? in0 : ((b == 1) ? in1 : in2);
    const float* __restrict__ W  = (b == 0) ? w0  : ((b == 1) ? w1  : w2);
    const int tid = threadIdx.x;
    const int row0 = blockIdx.x * 128;

    {
        const float4* __restrict__ w4 = (const float4*)W;
        float4* sw4 = (float4*)sW;
        #pragma unroll
        for (int j = 0; j < 4; ++j) sw4[j * 256 + tid] = w4[j * 256 + tid];
    }
    if (row0 + 128 <= N) {
        const float4* __restrict__ in4 = (const float4*)(in + (size_t)row0 * 64);
        #pragma unroll
        for (int j = 0; j < 8; ++j) {
            const int idx = j * 256 + tid;     // 0..2047
            const int row = idx >> 4;          // 16 float4 per row
            const int kc4 = idx & 15;
            const float4 v = in4[idx];
            sxT[4 * kc4 + 0][row] = v.x;
            sxT[4 * kc4 + 1][row] = v.y;
            sxT[4 * kc4 + 2][row] = v.z;
            sxT[4 * kc4 + 3][row] = v.w;
        }
    } else {
        for (int j = 0; j < 8; ++j) {
            const int idx = j * 256 + tid;
            const int row = idx >> 4;
            const int kc4 = idx & 15;
            float4 v = make_float4(0.f, 0.f, 0.f, 0.f);
            if (row0 + row < N) v = ((const float4*)in)[(size_t)(row0 + row) * 16 + kc4];
            sxT[4 * kc4 + 0][row] = v.x;
            sxT[4 * kc4 + 1][row] = v.y;
            sxT[4 * kc4 + 2][row] = v.z;
            sxT[4 * kc4 + 3][row] = v.w;
        }
    }
    __syncthreads();

    const int tx = tid & 15;    // cols 4*tx .. 4*tx+3
    const int ty = tid >> 4;    // rows 8*ty .. 8*ty+7
    float acc[8][4];
    #pragma unroll
    for (int r = 0; r < 8; ++r)
        #pragma unroll
        for (int c = 0; c < 4; ++c) acc[r][c] = 0.f;

    #pragma unroll 2
    for (int k = 0; k < 64; ++k) {
        const float4 wv = *(const float4*)&sW[k * 64 + 4 * tx];
        const float4 xa = *(const float4*)&sxT[k][8 * ty];
        const float4 xb = *(const float4*)&sxT[k][8 * ty + 4];
        const float xr[8] = { xa.x, xa.y, xa.z, xa.w, xb.x, xb.y, xb.z, xb.w };
        #pragma unroll
        for (int r = 0; r < 8; ++r) {
            acc[r][0] = fmaf(xr[r], wv.x, acc[r][0]);
            acc[r][1] = fmaf(xr[r], wv.y, acc[r][1]);
            acc[r][2] = fmaf(xr[r], wv.z, acc[r][2]);
            acc[r][3] = fmaf(xr[r], wv.w, acc[r][3]);
        }
    }

    const float alpha = alphaF[0];
    #pragma unroll
    for (int r = 0; r < 8; ++r) {
        const int row = row0 + 8 * ty + r;
        if (row < N) {
            if (b < 2) {
                uint2 o;
                o.x = (unsigned int)f2bf(acc[r][0]) | ((unsigned int)f2bf(acc[r][1]) << 16);
                o.y = (unsigned int)f2bf(acc[r][2]) | ((unsigned int)f2bf(acc[r][3]) << 16);
                ((uint2*)Qb)[(size_t)row * 32 + b * 16 + tx] = o;
            } else {
                float4 o = make_float4(fmaxf(alpha * acc[r][0], 0.f),
                                       fmaxf(alpha * acc[r][1], 0.f),
                                       fmaxf(alpha * acc[r][2], 0.f),
                                       fmaxf(alpha * acc[r][3], 0.f));
                ((float4*)outF)[(size_t)row * 16 + tx] = o;
            }
        }
    }
}

// SPMM over fused N x 128 bf16 features. One wave per dest node; lane holds
// features (2*lane, 2*lane+1) as one u32. Lanes 0-31 -> homo, 32-63 -> het.
__global__ __launch_bounds__(256) void spmm1_kernel(
    const unsigned short* __restrict__ Pb, const unsigned short* __restrict__ bucket,
    const int* __restrict__ cnt, const float* __restrict__ dinv,
    float* __restrict__ homo1, float* __restrict__ het1,
    const float* __restrict__ aH, const float* __restrict__ aT, int N)
{
    const int i = blockIdx.x * 4 + (threadIdx.x >> 6);
    if (i >= N) return;
    const int lane = threadIdx.x & 63;
    const unsigned int* __restrict__ P4 = (const unsigned int*)Pb;
    const float di = dinv[i];
    const unsigned int pself = P4[(size_t)i * 64 + lane];
    const float psx = bflo(pself), psy = bfhi(pself);
    int n = cnt[i]; if (n > 64) n = 64;
    const unsigned short* __restrict__ brow = bucket + (size_t)i * 64;
    float ax = 0.f, ay = 0.f;
    for (int k0 = 0; k0 < n; k0 += 8) {
        #pragma unroll
        for (int j = 0; j < 8; ++j) {
            const int k = k0 + j;
            const bool act = (k < n);
            const int c = act ? (int)brow[k] : i;  // broadcast load (uniform)
            const float dc = act ? dinv[c] : 0.f;  // broadcast gather
            const unsigned int pv = P4[(size_t)c * 64 + lane];
            ax = fmaf(dc, bflo(pv), ax);
            ay = fmaf(dc, bfhi(pv), ay);
        }
    }
    const float yx = di * (ax + di * psx);
    const float yy = di * (ay + di * psy);
    float ox, oy; float* dst;
    if (lane < 32) {
        const float a = aH[0];
        ox = fmaxf(a * yx, 0.f); oy = fmaxf(a * yy, 0.f);
        dst = homo1 + (size_t)i * 64 + 2 * lane;
    } else {
        const float a = aT[0];
        ox = fmaxf(a * (psx - yx), 0.f); oy = fmaxf(a * (psy - yy), 0.f);
        dst = het1 + (size_t)i * 64 + 2 * (lane - 32);
    }
    *(float2*)dst = make_float2(ox, oy);
}

__global__ __launch_bounds__(256) void spmm2_kernel(
    const unsigned short* __restrict__ Qb, const unsigned short* __restrict__ bucket,
    const int* __restrict__ cnt, const float* __restrict__ dinv,
    const float* __restrict__ full2,
    float* __restrict__ outComb, float* __restrict__ outHomo, float* __restrict__ outHet,
    const float* __restrict__ aH, const float* __restrict__ aT,
    const float* __restrict__ wH, const float* __restrict__ wF, const float* __restrict__ wT,
    int N)
{
    const int i = blockIdx.x * 4 + (threadIdx.x >> 6);
    if (i >= N) return;
    const int lane = threadIdx.x & 63;
    const unsigned int* __restrict__ Q4 = (const unsigned int*)Qb;
    const float di = dinv[i];
    const unsigned int qself = Q4[(size_t)i * 64 + lane];
    const float qsx = bflo(qself), qsy = bfhi(qself);
    int n = cnt[i]; if (n > 64) n = 64;
    const unsigned short* __restrict__ brow = bucket + (size_t)i * 64;
    float ax = 0.f, ay = 0.f;
    for (int k0 = 0; k0 < n; k0 += 8) {
        #pragma unroll
        for (int j = 0; j < 8; ++j) {
            const int k = k0 + j;
            const bool act = (k < n);
            const int c = act ? (int)brow[k] : i;
            const float dc = act ? dinv[c] : 0.f;
            const unsigned int qv = Q4[(size_t)c * 64 + lane];
            ax = fmaf(dc, bflo(qv), ax);
            ay = fmaf(dc, bfhi(qv), ay);
        }
    }
    const float yx = di * (ax + di * qsx);
    const float yy = di * (ay + di * qsy);
    float vx, vy; float* dst;
    if (lane < 32) {
        const float a = aH[0];
        vx = fmaxf(a * yx, 0.f); vy = fmaxf(a * yy, 0.f);
        dst = outHomo + (size_t)i * 64 + 2 * lane;
    } else {
        const float a = aT[0];
        vx = fmaxf(a * (qsx - yx), 0.f); vy = fmaxf(a * (qsy - yy), 0.f);
        dst = outHet + (size_t)i * 64 + 2 * (lane - 32);
    }
    *(float2*)dst = make_float2(vx, vy);
    // combined = wH*h_homo + wF*h_full + wT*h_het; exchange halves across lane^32
    const float tx = __shfl_xor(vx, 32);
    const float ty = __shfl_xor(vy, 32);
    if (lane < 32) {
        const float2 f2 = ((const float2*)full2)[(size_t)i * 32 + lane];
        const float cwh = wH[0], cwf = wF[0], cwt = wT[0];
        const float cx = cwh * vx + cwf * f2.x + cwt * tx;
        const float cy = cwh * vy + cwf * f2.y + cwt * ty;
        *(float2*)(outComb + (size_t)i * 64 + 2 * lane) = make_float2(cx, cy);
    }
}

extern "C" void kernel_launch(void* const* d_in, const int* in_sizes, int n_in,
                              void* d_out, int out_size, void* d_ws, size_t ws_size,
                              hipStream_t stream)
{
    const float* x  = (const float*)d_in[0];
    const int*   ei = (const int*)d_in[1];
    const int N = in_sizes[0] / 128;
    const int E = in_sizes[1] / 2;
    const float* homo_W0 = (const float*)d_in[3];
    const float* homo_W1 = (const float*)d_in[4];
    const float* full_W0 = (const float*)d_in[5];
    const float* full_W1 = (const float*)d_in[6];
    const float* het_W0  = (const float*)d_in[7];
    const float* het_W1  = (const float*)d_in[8];
    const float* homo_a0 = (const float*)d_in[9];
    const float* homo_a1 = (const float*)d_in[10];
    const float* full_a0 = (const float*)d_in[11];
    const float* full_a1 = (const float*)d_in[12];
    const float* het_a0  = (const float*)d_in[13];
    const float* het_a1  = (const float*)d_in[14];
    const float* w_homo  = (const float*)d_in[15];
    const float* w_full  = (const float*)d_in[16];
    const float* w_het   = (const float*)d_in[17];

    char* ws = (char*)d_ws;
    size_t off = 0;
    auto alloc = [&](size_t bytes) -> char* {
        char* p = ws + off;
        off = (off + bytes + 511) & ~(size_t)511;
        return p;
    };
    int*            deg    = (int*)alloc((size_t)N * 4);
    int*            cur    = (int*)alloc((size_t)N * 4);
    float*          dinv   = (float*)alloc((size_t)N * 4);
    unsigned short* bucket = (unsigned short*)alloc((size_t)N * 64 * 2);
    unsigned short* Pb     = (unsigned short*)alloc((size_t)N * 128 * 2);
    float*          full1  = (float*)alloc((size_t)N * 64 * 4);
    float*          homo1  = (float*)alloc((size_t)N * 64 * 4);
    float*          het1   = (float*)alloc((size_t)N * 64 * 4);
    unsigned short* Qb     = Pb;  // Pb dead after spmm1; reuse for layer 2

    float* out      = (float*)d_out;
    float* outComb  = out;
    float* outHomo  = out + (size_t)N * 64;
    float* outFull  = out + (size_t)2 * N * 64;
    float* outHet   = out + (size_t)3 * N * 64;

    hipMemsetAsync(deg, 0, (size_t)N * 4, stream);
    hipMemsetAsync(cur, 0, (size_t)N * 4, stream);

    // XCD-partitioned adjacency build: 8 partitions x edge-chunks.
    const int psize = (N + 7) / 8;
    const int nchunks = (E + EDGES_PER_BLOCK - 1) / EDGES_PER_BLOCK;
    build_adj_kernel<<<nchunks * 8, 256, 0, stream>>>(ei, E, psize, deg, cur, bucket);
    dinv_kernel<<<(N + 255) / 256, 256, 0, stream>>>(deg, dinv, N);

    // Layer 1: Pb[:,0:64]=x@homo_W0, Pb[:,64:128]=x@het_W0 (bf16),
    //          full1=relu(af0*x@full_W0)
    gemm_l1_kernel<<<(N + 63) / 64, 256, 0, stream>>>(
        x, homo_W0, het_W0, full_W0, Pb, full1, full_a0, N);
    spmm1_kernel<<<(N + 3) / 4, 256, 0, stream>>>(
        Pb, bucket, cur, dinv, homo1, het1, homo_a0, het_a0, N);

    // Layer 2: Qb[:,0:64]=homo1@homo_W1, Qb[:,64:128]=het1@het_W1 (bf16),
    //          h_full = relu(af1*full1@full_W1) written straight to d_out
    gemm_l2_kernel<<<dim3((N + 127) / 128, 3), 256, 0, stream>>>(
        homo1, het1, full1, homo_W1, het_W1, full_W1, Qb, outFull, full_a1, N);
    spmm2_kernel<<<(N + 3) / 4, 256, 0, stream>>>(
        Qb, bucket, cur, dinv, outFull, outComb, outHomo, outHet,
        homo_a1, het_a1, w_homo, w_full, w_het, N);
}